// Round 8
// baseline (198.812 us; speedup 1.0000x reference)
//
#include <hip/hip_runtime.h>

// NCC weight loss, fused single-kernel. v9 (from v8 @ 82.9us):
//  - sx AoS split: sx4[row][col][4] holds (I,J,I2,J2) x-sums packed per column
//    (16B, b128-aligned); sx1[row][col] holds IJ. Phase C reads drop
//    35 b32 -> 7x(b128+b32) = 14 insts (C was 53% of the LDS-pipe budget).
//  - Phase B: same 5 b128 zsL reads + register transpose; writes 4xb128(sx4)
//    + 1xb128(sx1) = same 5 write insts.
//  - Everything else identical to v8: TH=24, C = 256thr x (1 col x 3 rows),
//    B left-neighbor+own-registers dedup, ZCH=16 queued grid (1120 blocks),
//    pipelined global prefetch, lgkm-only raw barriers.
// Dims fixed: (N=2, C=1, D=160, H=192, W=224), win=5, fp32.
#define N_  2
#define D_  160
#define H_  192
#define W_  224
#define TW  32            // output tile width  (x)
#define TH  24            // output tile height (y)
#define ZCH 16            // z-chunk per block
#define NZC (D_/ZCH)      // 10
#define HR  (TH+4)        // 28 halo rows
#define HC  (TW+4)        // 36 halo cols (zsL row stride, 144B 16B-aligned)
#define PL  (H_*W_)       // 43008 plane stride
#define TOT (N_*D_*H_*W_) // 13,762,560

#define BAR() asm volatile("s_waitcnt lgkmcnt(0)\n\ts_barrier" ::: "memory")

__global__ __launch_bounds__(256, 4) void ncc_kernel(
    const float* __restrict__ I, const float* __restrict__ J,
    const float* __restrict__ Wm, float* __restrict__ out)
{
    __shared__ __align__(16) float zsL[5][HR][HC];   // z-sums (SoA), 20160 B
    __shared__ __align__(16) float sx4[HR][TW][4];   // x-sums AoS(I,J,I2,J2), 14336 B
    __shared__ __align__(16) float sx1[HR][TW];      // x-sums IJ, 3584 B
    __shared__ float red[4];

    const int tid = threadIdx.x;
    const int bx = blockIdx.x, by = blockIdx.y;
    const int n  = blockIdx.z / NZC;
    const int c0 = (blockIdx.z % NZC) * ZCH;
    const int nbase = n * D_ * PL;

    // ---- Phase A: 252 threads, 4 halo columns each (two aligned float2 loads)
    const bool aAct = tid < 252;
    const int arow = tid / 9;                 // 0..27
    const int ag   = tid % 9;                 // 0..8
    const int ah   = by * TH - 2 + arow;
    const int ahc  = min(max(ah, 0), H_ - 1);
    const int aw0  = bx * TW - 2 + 4 * ag;    // even
    const bool mH  = (ah == ahc);
    const bool mW0 = (aw0 >= 0);              // pair0 = cols aw0, aw0+1
    const bool mW1 = (aw0 + 3 < W_);          // pair1 = cols aw0+2, aw0+3
    const int awc0 = max(aw0, 0);
    const int awc1 = min(aw0 + 2, W_ - 4);
    const int preA0 = nbase + ahc * W_ + awc0;   // + z*PL
    const int preA1 = nbase + ahc * W_ + awc1;

    // ---- Phase B: same threads as A, g>=1 active (left-b128 + own registers)
    const bool bAct = aAct && (ag >= 1);

    // ---- Phase C: 256 threads, 1 col x 3 y-rows each (7-row window)
    const int cg   = tid >> 5;                // 0..7 (row triple)
    const int cr0  = 3 * cg;                  // local top row 0,3,...,21
    const int ccol = tid & 31;                // 0..31
    const int ch0  = by * TH + cr0;
    const int cw   = bx * TW + ccol;
    const int preW = nbase + ch0 * W_ + cw;   // + zo*PL ; rows +W_, +2*W_

    // per-column z-ring of raw I,J (5 deep) + incremental z-sums (5 quantities)
    float rI[4][5], rJ[4][5], zs[5][4];
#pragma unroll
    for (int c = 0; c < 4; ++c)
#pragma unroll
        for (int k = 0; k < 5; ++k) { rI[c][k] = 0.f; rJ[c][k] = 0.f; }
#pragma unroll
    for (int a = 0; a < 5; ++a)
#pragma unroll
        for (int c = 0; c < 4; ++c) zs[a][c] = 0.f;

    float acc = 0.f;
    const float inv125 = 1.0f / 125.0f;

    // current-plane raw values (masked), consumed by this iteration's Phase A
    float cI[4] = {0.f,0.f,0.f,0.f}, cJ[4] = {0.f,0.f,0.f,0.f};
    {
        const int z0 = c0 - 2;
        const int zc = min(max(z0, 0), D_ - 1);
        const bool mZ = (z0 == zc);
        const int zoff = zc * PL;
        if (aAct) {
            const float2 i0 = *(const float2*)&I[preA0 + zoff];
            const float2 i1 = *(const float2*)&I[preA1 + zoff];
            const float2 j0 = *(const float2*)&J[preA0 + zoff];
            const float2 j1 = *(const float2*)&J[preA1 + zoff];
            const float f0 = (mH && mW0 && mZ) ? 1.f : 0.f;
            const float f1 = (mH && mW1 && mZ) ? 1.f : 0.f;
            cI[0]=i0.x*f0; cI[1]=i0.y*f0; cI[2]=i1.x*f1; cI[3]=i1.y*f1;
            cJ[0]=j0.x*f0; cJ[1]=j0.y*f0; cJ[2]=j1.x*f1; cJ[3]=j1.y*f1;
        }
    }
    float wm0 = 0.f, wm1 = 0.f, wm2 = 0.f;  // Wm rows for this iter's Phase C

    for (int s = 0; s < ZCH + 4; ++s) {
        // ---- prefetch next z-plane (z+1) into registers — clamped + masked;
        //      stays in flight across both barriers (lgkm-only waits)
        const int zn  = c0 - 1 + s;
        const int znc = min(max(zn, 0), D_ - 1);
        const bool mZn = (zn == znc);
        const int zoffn = znc * PL;
        float2 pi0, pi1, pj0, pj1;
        if (aAct) {
            pi0 = *(const float2*)&I[preA0 + zoffn];
            pi1 = *(const float2*)&I[preA1 + zoffn];
            pj0 = *(const float2*)&J[preA0 + zoffn];
            pj1 = *(const float2*)&J[preA1 + zoffn];
        } else {
            pi0 = pi1 = pj0 = pj1 = make_float2(0.f, 0.f);
        }
        // ---- prefetch next iteration's Wm rows (clamped z, all threads)
        const int zon  = c0 - 3 + s;
        const int zonc = min(max(zon, 0), D_ - 1);
        const int wmo  = preW + zonc * PL;
        const float wn0 = Wm[wmo];
        const float wn1 = Wm[wmo + W_];
        const float wn2 = Wm[wmo + 2 * W_];

        // ---- Phase A: integrate current plane into z-ring, stage z-sums (b128)
        if (aAct) {
#pragma unroll
            for (int c = 0; c < 4; ++c) {
                const float vi = cI[c], vj = cJ[c];
                const float oi = rI[c][0], oj = rJ[c][0];
                zs[0][c] += vi - oi;
                zs[1][c] += vj - oj;
                zs[2][c] += vi*vi - oi*oi;
                zs[3][c] += vj*vj - oj*oj;
                zs[4][c] += vi*vj - oi*oj;
#pragma unroll
                for (int k = 0; k < 4; ++k) { rI[c][k]=rI[c][k+1]; rJ[c][k]=rJ[c][k+1]; }
                rI[c][4] = vi; rJ[c][4] = vj;
            }
#pragma unroll
            for (int a = 0; a < 5; ++a)
                *(float4*)&zsL[a][arow][4*ag] =
                    make_float4(zs[a][0], zs[a][1], zs[a][2], zs[a][3]);
        }
        BAR();   // lgkm drain only — prefetched globals stay in flight

        // ---- Phase B: x box-sum from left-neighbor b128 + own registers,
        //      then AoS transpose-write: 4xb128 (sx4) + 1xb128 (sx1).
        if (bAct) {
            float4 va[5];
#pragma unroll
            for (int a = 0; a < 5; ++a) {
                const float4 L = *(const float4*)&zsL[a][arow][4*ag - 4];
                const float o0 = zs[a][0], o1 = zs[a][1];
                const float o2 = zs[a][2], o3 = zs[a][3];
                const float m    = L.y + L.z + L.w;
                const float s01  = o0 + o1;
                const float s012 = s01 + o2;
                va[a] = make_float4(L.x + m + o0,
                                    m + s01,
                                    (L.z + L.w) + s012,
                                    L.w + (s012 + o3));
            }
            const int bc = 4 * ag - 4;
            *(float4*)&sx4[arow][bc    ][0] = make_float4(va[0].x, va[1].x, va[2].x, va[3].x);
            *(float4*)&sx4[arow][bc + 1][0] = make_float4(va[0].y, va[1].y, va[2].y, va[3].y);
            *(float4*)&sx4[arow][bc + 2][0] = make_float4(va[0].z, va[1].z, va[2].z, va[3].z);
            *(float4*)&sx4[arow][bc + 3][0] = make_float4(va[0].w, va[1].w, va[2].w, va[3].w);
            *(float4*)&sx1[arow][bc] = va[4];
        }
        BAR();

        // ---- Phase C: 7-row sliding y-sum, AoS reads: b128+b32 per row
        if (s >= 4) {   // uniform: output plane zo = c0-4+s is in range
            float4 q0 = *(const float4*)&sx4[cr0    ][ccol][0];
            float4 q1 = *(const float4*)&sx4[cr0 + 1][ccol][0];
            float4 q2 = *(const float4*)&sx4[cr0 + 2][ccol][0];
            float4 q3 = *(const float4*)&sx4[cr0 + 3][ccol][0];
            float4 q4 = *(const float4*)&sx4[cr0 + 4][ccol][0];
            float4 q5 = *(const float4*)&sx4[cr0 + 5][ccol][0];
            float4 q6 = *(const float4*)&sx4[cr0 + 6][ccol][0];
            const float t0 = sx1[cr0    ][ccol];
            const float t1 = sx1[cr0 + 1][ccol];
            const float t2 = sx1[cr0 + 2][ccol];
            const float t3 = sx1[cr0 + 3][ccol];
            const float t4 = sx1[cr0 + 4][ccol];
            const float t5 = sx1[cr0 + 5][ccol];
            const float t6 = sx1[cr0 + 6][ccol];

            float4 S0;   // rows cr0..cr0+4: (I_sum, J_sum, I2_sum, J2_sum)
            S0.x = ((q0.x + q1.x) + (q2.x + q3.x)) + q4.x;
            S0.y = ((q0.y + q1.y) + (q2.y + q3.y)) + q4.y;
            S0.z = ((q0.z + q1.z) + (q2.z + q3.z)) + q4.z;
            S0.w = ((q0.w + q1.w) + (q2.w + q3.w)) + q4.w;
            const float T0 = ((t0 + t1) + (t2 + t3)) + t4;     // IJ_sum

            float4 S1;   // rows cr0+1..cr0+5
            S1.x = S0.x - q0.x + q5.x;  S1.y = S0.y - q0.y + q5.y;
            S1.z = S0.z - q0.z + q5.z;  S1.w = S0.w - q0.w + q5.w;
            const float T1 = T0 - t0 + t5;

            float4 S2;   // rows cr0+2..cr0+6
            S2.x = S1.x - q1.x + q6.x;  S2.y = S1.y - q1.y + q6.y;
            S2.z = S1.z - q1.z + q6.z;  S2.w = S1.w - q1.w + q6.w;
            const float T2 = T1 - t1 + t6;

            {
                const float cr = T0 - S0.x * S0.y * inv125;
                const float vi = S0.z - S0.x * S0.x * inv125;
                const float vj = S0.w - S0.y * S0.y * inv125;
                acc += wm0 * (cr * cr) * __builtin_amdgcn_rcpf(vi * vj + 1e-8f);
            }
            {
                const float cr = T1 - S1.x * S1.y * inv125;
                const float vi = S1.z - S1.x * S1.x * inv125;
                const float vj = S1.w - S1.y * S1.y * inv125;
                acc += wm1 * (cr * cr) * __builtin_amdgcn_rcpf(vi * vj + 1e-8f);
            }
            {
                const float cr = T2 - S2.x * S2.y * inv125;
                const float vi = S2.z - S2.x * S2.x * inv125;
                const float vj = S2.w - S2.y * S2.y * inv125;
                acc += wm2 * (cr * cr) * __builtin_amdgcn_rcpf(vi * vj + 1e-8f);
            }
        }

        // ---- rotate pipeline registers (apply masks to prefetched plane)
        {
            const float f0 = (mH && mW0 && mZn) ? 1.f : 0.f;
            const float f1 = (mH && mW1 && mZn) ? 1.f : 0.f;
            cI[0]=pi0.x*f0; cI[1]=pi0.y*f0; cI[2]=pi1.x*f1; cI[3]=pi1.y*f1;
            cJ[0]=pj0.x*f0; cJ[1]=pj0.y*f0; cJ[2]=pj1.x*f1; cJ[3]=pj1.y*f1;
        }
        wm0 = wn0; wm1 = wn1; wm2 = wn2;
        // Hazards: C reads sx4/sx1 vs next B writes them -> separated by next
        // BAR1 (A-phase barrier). Next A writes zsL vs this B reads zsL ->
        // separated by BAR2. B reads own zs registers (no hazard).
    }

    // Block reduction: wave64 shuffle, then cross-wave via LDS
#pragma unroll
    for (int off = 32; off > 0; off >>= 1)
        acc += __shfl_down(acc, off, 64);
    const int wave = tid >> 6;
    const int lane = tid & 63;
    if (lane == 0) red[wave] = acc;
    __syncthreads();
    if (tid == 0) {
        const float t = red[0] + red[1] + red[2] + red[3];
        atomicAdd(out, t * (-1.0f / (float)TOT));
    }
}

extern "C" void kernel_launch(void* const* d_in, const int* in_sizes, int n_in,
                              void* d_out, int out_size, void* d_ws, size_t ws_size,
                              hipStream_t stream)
{
    const float* I  = (const float*)d_in[0];
    const float* J  = (const float*)d_in[1];
    const float* Wm = (const float*)d_in[2];
    float* out = (float*)d_out;

    hipMemsetAsync(out, 0, sizeof(float), stream);

    dim3 grid(W_ / TW, H_ / TH, N_ * NZC);  // (7, 8, 20) = 1120 blocks
    dim3 block(256);
    hipLaunchKernelGGL(ncc_kernel, grid, block, 0, stream, I, J, Wm, out);
}